// Round 1
// baseline (245.756 us; speedup 1.0000x reference)
//
#include <hip/hip_runtime.h>

// SpinConvSq2d: 5x5 wrap conv with SO(3) channel structure.
// Per-pixel outputs (128 ch): out0[w] (32) + out1[w,i] (96).
// Factorized form (sh1 is per-output-pixel, so dot/cross factor out of the
// (a,u) contraction):
//   S000[w] = sum_au x0  * W000,   S011[w] = sum_au x0  * W011
//   V[w,i]  = sum_au x1_i * W110
//   T[w,i]  = sum_au x1_i * W101
//   U[w,i]  = sum_au x1_i * W111
//   out0[w]   = A0*( SH0*S000 + CG110 * sum_i sh1_i * V[w,i] )
//   out1[w,i] = A1*( sh1_i*S011 + SH0*T[w,i] + CG111*(U[w,:] x sh1)_i )

#define LSZ 64
#define NCH 64

__device__ __forceinline__ int wrap64(int v) { return v & 63; }

__global__ __launch_bounds__(256) void spinconv_fp32_kernel(
    const float* __restrict__ feat, const float* __restrict__ spin,
    const float* __restrict__ W000, const float* __restrict__ W110,
    const float* __restrict__ W011, const float* __restrict__ W101,
    const float* __restrict__ W111, float* __restrict__ out)
{
    const float SH0f   = 0.28209479177387814f;  // 1/(2 sqrt(pi))
    const float SH1f   = 0.4886025119029199f;   // sqrt(3/(4 pi))
    const float CG110f = 0.5773502691896258f;   // 1/sqrt(3)
    const float CG111f = 0.7071067811865476f;   // 1/sqrt(2)
    const float A0f    = 0.035355339059327376f; // 1/sqrt(800)
    const float A1f    = 0.028867513459481287f; // 1/sqrt(1200)

    // Block handles 8 pixels along y (same n, same x) x 32 output channels w.
    int blk  = blockIdx.x;            // 0..4095
    int ygrp = blk & 7;
    int nx   = blk >> 3;
    int x    = nx & 63;
    int n    = nx >> 6;
    int y0   = ygrp * 8;

    __shared__ float fl[5][12][NCH];         // feat tile: x-2..x+2, y0-2..y0+9
    __shared__ float wl[5][16][32];          // weights for current 'a': 5 arrays

    int tid = threadIdx.x;

    // ---- stage feat tile (3840 floats, 15 per thread) ----
    #pragma unroll
    for (int k = 0; k < 15; ++k) {
        int e   = tid + k * 256;
        int xx  = e / (12 * NCH);
        int rem = e - xx * (12 * NCH);
        int yy  = rem / NCH;
        int ch  = rem - yy * NCH;
        int X = wrap64(x + xx - 2 + 64);
        int Y = wrap64(y0 + yy - 2 + 64);
        fl[xx][yy][ch] = feat[(((n * 64 + X) * 64 + Y) * 64) + ch];
    }

    int w   = tid & 31;
    int pix = tid >> 5;

    float S000 = 0.f, S011 = 0.f;
    float V0 = 0.f, V1 = 0.f, V2 = 0.f;
    float T0 = 0.f, T1 = 0.f, T2 = 0.f;
    float U0 = 0.f, U1 = 0.f, U2 = 0.f;

    for (int a = 0; a < 25; ++a) {
        __syncthreads();   // previous wl use done (and, at a==0, feat visible after next sync)
        // stage the 5 weight slabs for this 'a': 5*512 = 2560 floats, 10/thread
        #pragma unroll
        for (int k = 0; k < 10; ++k) {
            int e   = tid + k * 256;
            int arr = e >> 9;          // 0..4
            int rem = e & 511;         // u*32 + w
            const float* Wp = (arr == 0) ? W000 : (arr == 1) ? W110
                             : (arr == 2) ? W011 : (arr == 3) ? W101 : W111;
            ((float*)wl)[e] = Wp[a * 512 + rem];
        }
        __syncthreads();

        int ix = a / 5;
        int iy = a - ix * 5;
        const float* fb = &fl[ix][pix + iy][0];

        #pragma unroll
        for (int u = 0; u < 16; ++u) {
            float x0  = fb[u];
            float x1a = fb[16 + 3 * u];
            float x1b = fb[17 + 3 * u];
            float x1c = fb[18 + 3 * u];
            float w000 = wl[0][u][w];
            float w110 = wl[1][u][w];
            float w011 = wl[2][u][w];
            float w101 = wl[3][u][w];
            float w111 = wl[4][u][w];
            S000 = fmaf(x0,  w000, S000);
            S011 = fmaf(x0,  w011, S011);
            V0   = fmaf(x1a, w110, V0);
            V1   = fmaf(x1b, w110, V1);
            V2   = fmaf(x1c, w110, V2);
            T0   = fmaf(x1a, w101, T0);
            T1   = fmaf(x1b, w101, T1);
            T2   = fmaf(x1c, w101, T2);
            U0   = fmaf(x1a, w111, U0);
            U1   = fmaf(x1b, w111, U1);
            U2   = fmaf(x1c, w111, U2);
        }
    }

    // ---- epilogue ----
    int y = y0 + pix;
    int pixidx = (n * 64 + x) * 64 + y;
    float s0 = SH1f * spin[pixidx * 3 + 0];
    float s1 = SH1f * spin[pixidx * 3 + 1];
    float s2 = SH1f * spin[pixidx * 3 + 2];

    float out0 = A0f * (SH0f * S000 + CG110f * (s0 * V0 + s1 * V1 + s2 * V2));

    // cross(U, sh1)
    float c0 = U1 * s2 - U2 * s1;
    float c1 = U2 * s0 - U0 * s2;
    float c2 = U0 * s1 - U1 * s0;

    float o1_0 = A1f * (s0 * S011 + SH0f * T0 + CG111f * c0);
    float o1_1 = A1f * (s1 * S011 + SH0f * T1 + CG111f * c1);
    float o1_2 = A1f * (s2 * S011 + SH0f * T2 + CG111f * c2);

    float* op = out + (size_t)pixidx * 128;
    op[w]              = out0;
    op[32 + w * 3 + 0] = o1_0;
    op[32 + w * 3 + 1] = o1_1;
    op[32 + w * 3 + 2] = o1_2;
}

extern "C" void kernel_launch(void* const* d_in, const int* in_sizes, int n_in,
                              void* d_out, int out_size, void* d_ws, size_t ws_size,
                              hipStream_t stream) {
    const float* feat = (const float*)d_in[0];
    const float* spin = (const float*)d_in[1];
    const float* W000 = (const float*)d_in[2];
    const float* W110 = (const float*)d_in[3];
    const float* W011 = (const float*)d_in[4];
    const float* W101 = (const float*)d_in[5];
    const float* W111 = (const float*)d_in[6];
    float* out = (float*)d_out;

    hipLaunchKernelGGL(spinconv_fp32_kernel, dim3(4096), dim3(256), 0, stream,
                       feat, spin, W000, W110, W011, W101, W111, out);
}

// Round 2
// 35.753 us; speedup vs baseline: 6.8736x; 6.8736x over previous
//
#include <hip/hip_runtime.h>

// SpinConvSq2d via MFMA (bf16).
// Factorized: S000,S011 = x0 x {W000,W011}; V,T,U[i] = x1_i x {W110,W101,W111}
// GEMM per 5x5 tap a: K=16 (u), M=32 pixels/wave, N in {64 (x0), 96 (x1)}.
// out0   = A0*(SH0*S000 + CG110*dot(s,V))
// out1_i = A1*(s_i*S011 + SH0*T_i + CG111*cross(U,s)_i),  s = SH1*spin

typedef __attribute__((ext_vector_type(8))) short short8;
typedef __attribute__((ext_vector_type(16))) float f32x16;
typedef __attribute__((ext_vector_type(4))) unsigned int uint4v;

#define FEATT_BYTES (8u * 64u * 64u * 64u * 2u)   // 4,194,304 B bf16 feat
#define BT_OFFSET   FEATT_BYTES                    // Bt blob: 25*160*16*2 = 128,000 B

#define MFMA32(A, B, C) __builtin_amdgcn_mfma_f32_32x32x16_bf16(A, B, C, 0, 0, 0)

__device__ __forceinline__ unsigned short f2bf(float f) {
    unsigned int u = __float_as_uint(f);
    return (unsigned short)((u + 0x7FFFu + ((u >> 16) & 1u)) >> 16);  // RNE
}

// ---------------- prep: feat->bf16 reordered, weights->bf16 transposed ----------------
__global__ __launch_bounds__(256) void prep_kernel(
    const float* __restrict__ feat,
    const float* __restrict__ W000, const float* __restrict__ W110,
    const float* __restrict__ W011, const float* __restrict__ W101,
    const float* __restrict__ W111,
    unsigned char* __restrict__ ws)
{
    int tid = threadIdx.x;
    int b = blockIdx.x;
    if (b < 128) {
        // featT[px][ch']: ch' 0-15 = x0[u]; 16+16i+u = x1 comp i, u
        int px = b * 256 + tid;
        const float* src = feat + (size_t)px * 64;
        unsigned short* dst = (unsigned short*)ws + (size_t)px * 64;
        #pragma unroll
        for (int cb = 0; cb < 8; ++cb) {
            short8 v;
            #pragma unroll
            for (int j = 0; j < 8; ++j) {
                int chp = cb * 8 + j;
                int c = (chp < 16) ? chp : (16 + 3 * ((chp - 16) & 15) + ((chp - 16) >> 4));
                v[j] = (short)f2bf(src[c]);
            }
            *(short8*)(dst + cb * 8) = v;
        }
    } else {
        // Bt[a][colv][k] bf16; colv: 0-31 W000, 32-63 W011, 64-95 W110, 96-127 W101, 128-159 W111
        int t = (b - 128) * 256 + tid;     // 0..63999
        int a = t / 2560;
        int rem = t - a * 2560;
        int colv = rem >> 4;
        int k = rem & 15;
        int arr = colv >> 5;
        int w = colv & 31;
        const float* Wp = (arr == 0) ? W000 : (arr == 1) ? W011
                        : (arr == 2) ? W110 : (arr == 3) ? W101 : W111;
        ((unsigned short*)(ws + BT_OFFSET))[t] = f2bf(Wp[a * 512 + k * 32 + w]);
    }
}

// ---------------- main MFMA kernel ----------------
__global__ __launch_bounds__(128, 2) void spinconv_mfma_kernel(
    const unsigned char* __restrict__ ws,
    const float* __restrict__ spin,
    float* __restrict__ out)
{
    const float SH0f   = 0.28209479177387814f;
    const float CG110f = 0.5773502691896258f;
    const float CG111f = 0.7071067811865476f;
    const float A0f    = 0.035355339059327376f;
    const float A1f    = 0.028867513459481287f;

    __shared__ __align__(16) unsigned char fl[5 * 64 * 128];  // 40 KB swizzled feat tile
    __shared__ float s_lds[192];                              // SH1*spin for 64 pixels

    int tid = threadIdx.x;
    int bid = blockIdx.x;          // n*64 + x
    int x = bid & 63;

    const unsigned short* featT = (const unsigned short*)ws;
    const unsigned char* bt = ws + BT_OFFSET;

    // ---- stage 5 wrapped feat columns, XOR-swizzled: slot' = slot ^ (y&7) ----
    #pragma unroll
    for (int kk = 0; kk < 20; ++kk) {
        int e = tid + (kk << 7);   // 0..2559 (16B chunks)
        int dx = e >> 9;
        int rem = e & 511;
        int y = rem >> 3;
        int s = rem & 7;
        int X = (x + dx + 62) & 63;
        size_t px = ((size_t)(bid - x + X)) * 64 + y;   // (n*64+X)*64 + y
        uint4v v = *((const uint4v*)(featT + px * 64) + s);
        *(uint4v*)(fl + dx * 8192 + y * 128 + ((s ^ (y & 7)) << 4)) = v;
    }
    for (int e = tid; e < 192; e += 128) {
        s_lds[e] = 0.4886025119029199f * spin[(size_t)bid * 192 + e];
    }
    __syncthreads();

    int lane = tid & 63;
    int wv = tid >> 6;             // wave: pixel half
    int col = lane & 31;           // N-col (w) and A-row (pixel within tile)
    int khalf = lane >> 5;         // K-half select
    int yb = wv << 5;

    f32x16 zz;
    #pragma unroll
    for (int i = 0; i < 16; ++i) zz[i] = 0.f;
    f32x16 aS000 = zz, aS011 = zz;
    f32x16 aV0 = zz, aV1 = zz, aV2 = zz;
    f32x16 aT0 = zz, aT1 = zz, aT2 = zz;
    f32x16 aU0 = zz, aU1 = zz, aU2 = zz;

    const unsigned char* bbase = bt + col * 32 + khalf * 16;
    auto loadB = [&](int a, short8* B) {
        const unsigned char* p = bbase + a * 5120;
        B[0] = *(const short8*)(p);
        B[1] = *(const short8*)(p + 1024);
        B[2] = *(const short8*)(p + 2048);
        B[3] = *(const short8*)(p + 3072);
        B[4] = *(const short8*)(p + 4096);
    };

    auto body = [&](int a, short8* Bc, short8* Bn) {
        if (a + 1 < 25) loadB(a + 1, Bn);    // prefetch next tap's weights (L2)
        int ix = a / 5;
        int iy = a - ix * 5;
        int yn = (yb + col + iy + 62) & 63;  // wrapped neighbor row (A-row = lane&31)
        const unsigned char* ab = fl + ix * 8192 + yn * 128;
        int xr = (yn & 7) << 4;
        short8 ax0 = *(const short8*)(ab + ((khalf << 4) ^ xr));
        short8 ac0 = *(const short8*)(ab + (((2 + khalf) << 4) ^ xr));
        short8 ac1 = *(const short8*)(ab + (((4 + khalf) << 4) ^ xr));
        short8 ac2 = *(const short8*)(ab + (((6 + khalf) << 4) ^ xr));
        aS000 = MFMA32(ax0, Bc[0], aS000);
        aS011 = MFMA32(ax0, Bc[1], aS011);
        aV0   = MFMA32(ac0, Bc[2], aV0);
        aT0   = MFMA32(ac0, Bc[3], aT0);
        aU0   = MFMA32(ac0, Bc[4], aU0);
        aV1   = MFMA32(ac1, Bc[2], aV1);
        aT1   = MFMA32(ac1, Bc[3], aT1);
        aU1   = MFMA32(ac1, Bc[4], aU1);
        aV2   = MFMA32(ac2, Bc[2], aV2);
        aT2   = MFMA32(ac2, Bc[3], aT2);
        aU2   = MFMA32(ac2, Bc[4], aU2);
    };

    short8 B0[5], B1[5];
    loadB(0, B0);
    for (int ap = 0; ap < 25; ap += 2) {
        body(ap, B0, B1);
        if (ap + 1 < 25) body(ap + 1, B1, B0);
    }

    // ---- epilogue: C/D row = (r&3) + 8*(r>>2) + 4*khalf, col = lane&31 ----
    int p0 = bid << 6;
    #pragma unroll
    for (int r = 0; r < 16; ++r) {
        int row = (r & 3) + ((r >> 2) << 3) + (khalf << 2);
        int y = yb + row;
        float s0 = s_lds[y * 3 + 0];
        float s1 = s_lds[y * 3 + 1];
        float s2 = s_lds[y * 3 + 2];
        float S000 = aS000[r], S011 = aS011[r];
        float V0 = aV0[r], V1 = aV1[r], V2 = aV2[r];
        float T0 = aT0[r], T1 = aT1[r], T2 = aT2[r];
        float U0 = aU0[r], U1 = aU1[r], U2 = aU2[r];

        float o0 = A0f * (SH0f * S000 + CG110f * (s0 * V0 + s1 * V1 + s2 * V2));
        float c0 = U1 * s2 - U2 * s1;
        float c1 = U2 * s0 - U0 * s2;
        float c2 = U0 * s1 - U1 * s0;
        float o10 = A1f * (s0 * S011 + SH0f * T0 + CG111f * c0);
        float o11 = A1f * (s1 * S011 + SH0f * T1 + CG111f * c1);
        float o12 = A1f * (s2 * S011 + SH0f * T2 + CG111f * c2);

        float* op = out + (size_t)(p0 + y) * 128;
        op[col] = o0;
        op[32 + 3 * col + 0] = o10;
        op[32 + 3 * col + 1] = o11;
        op[32 + 3 * col + 2] = o12;
    }
}

extern "C" void kernel_launch(void* const* d_in, const int* in_sizes, int n_in,
                              void* d_out, int out_size, void* d_ws, size_t ws_size,
                              hipStream_t stream) {
    const float* feat = (const float*)d_in[0];
    const float* spin = (const float*)d_in[1];
    const float* W000 = (const float*)d_in[2];
    const float* W110 = (const float*)d_in[3];
    const float* W011 = (const float*)d_in[4];
    const float* W101 = (const float*)d_in[5];
    const float* W111 = (const float*)d_in[6];
    float* out = (float*)d_out;
    unsigned char* ws = (unsigned char*)d_ws;

    hipLaunchKernelGGL(prep_kernel, dim3(378), dim3(256), 0, stream,
                       feat, W000, W110, W011, W101, W111, ws);
    hipLaunchKernelGGL(spinconv_mfma_kernel, dim3(512), dim3(128), 0, stream,
                       ws, spin, out);
}

// Round 3
// 29.240 us; speedup vs baseline: 8.4049x; 1.2228x over previous
//
#include <hip/hip_runtime.h>

// SpinConvSq2d via MFMA (bf16), N-split across wave pairs for 2x occupancy.
// Factorized: S000,S011 = x0 x {W000,W011}; V,T,U[i] = x1_i x {W110,W101,W111}
// Role A (even wave): S000,S011,V0..2   (mats W000,W011,W110)
// Role B (odd wave):  T0..2,U0..2       (mats W101,W111)
// out0   = A0*(SH0*S000 + CG110*dot(s,V))
// out1_i = A1*(s_i*S011 + SH0*T_i + CG111*cross(U,s)_i),  s = SH1*spin
// S011 crosses from role A to role B via LDS (one barrier).

typedef __attribute__((ext_vector_type(8))) short short8;
typedef __attribute__((ext_vector_type(16))) float f32x16;
typedef __attribute__((ext_vector_type(4))) unsigned int uint4v;

#define FEATT_BYTES (8u * 64u * 64u * 64u * 2u)   // 4,194,304 B bf16 feat
#define BT_OFFSET   FEATT_BYTES                    // Bt blob: 25*160*16*2 = 128,000 B

#define MFMA32(A, B, C) __builtin_amdgcn_mfma_f32_32x32x16_bf16(A, B, C, 0, 0, 0)

__device__ __forceinline__ unsigned short f2bf(float f) {
    unsigned int u = __float_as_uint(f);
    return (unsigned short)((u + 0x7FFFu + ((u >> 16) & 1u)) >> 16);  // RNE
}

// ---------------- prep: feat->bf16 reordered, weights->bf16 transposed ----------------
__global__ __launch_bounds__(256) void prep_kernel(
    const float* __restrict__ feat,
    const float* __restrict__ W000, const float* __restrict__ W110,
    const float* __restrict__ W011, const float* __restrict__ W101,
    const float* __restrict__ W111,
    unsigned char* __restrict__ ws)
{
    int tid = threadIdx.x;
    int b = blockIdx.x;
    if (b < 128) {
        // featT[px][ch']: ch' 0-15 = x0[u]; 16+16i+u = x1 comp i, u
        int px = b * 256 + tid;
        const float* src = feat + (size_t)px * 64;
        unsigned short* dst = (unsigned short*)ws + (size_t)px * 64;
        #pragma unroll
        for (int cb = 0; cb < 8; ++cb) {
            short8 v;
            #pragma unroll
            for (int j = 0; j < 8; ++j) {
                int chp = cb * 8 + j;
                int c = (chp < 16) ? chp : (16 + 3 * ((chp - 16) & 15) + ((chp - 16) >> 4));
                v[j] = (short)f2bf(src[c]);
            }
            *(short8*)(dst + cb * 8) = v;
        }
    } else {
        // Bt[a][colv][k] bf16; colv: 0-31 W000, 32-63 W011, 64-95 W110, 96-127 W101, 128-159 W111
        int t = (b - 128) * 256 + tid;     // 0..63999
        int a = t / 2560;
        int rem = t - a * 2560;
        int colv = rem >> 4;
        int k = rem & 15;
        int arr = colv >> 5;
        int w = colv & 31;
        const float* Wp = (arr == 0) ? W000 : (arr == 1) ? W011
                        : (arr == 2) ? W110 : (arr == 3) ? W101 : W111;
        ((unsigned short*)(ws + BT_OFFSET))[t] = f2bf(Wp[a * 512 + k * 32 + w]);
    }
}

// ---------------- main MFMA kernel ----------------
__global__ __launch_bounds__(256, 2) void spinconv_mfma_kernel(
    const unsigned char* __restrict__ ws,
    const float* __restrict__ spin,
    float* __restrict__ out)
{
    const float SH0f   = 0.28209479177387814f;
    const float CG110f = 0.5773502691896258f;
    const float CG111f = 0.7071067811865476f;
    const float A0f    = 0.035355339059327376f;
    const float A1f    = 0.028867513459481287f;

    __shared__ __align__(16) unsigned char fl[5 * 64 * 128];  // 40 KB swizzled feat tile
    __shared__ float sbuf[2][16][64];                         // 8 KB: S011 handoff A->B
    __shared__ float s_lds[192];                              // SH1*spin for 64 pixels

    int tid = threadIdx.x;
    int bid = blockIdx.x;          // n*64 + x
    int x = bid & 63;

    const unsigned short* featT = (const unsigned short*)ws;
    const unsigned char* bt = ws + BT_OFFSET;

    // ---- stage 5 wrapped feat columns, XOR-swizzled: slot' = slot ^ (y&7) ----
    #pragma unroll
    for (int kk = 0; kk < 10; ++kk) {
        int e = tid + (kk << 8);   // 0..2559 (16B chunks)
        int dx = e >> 9;
        int rem = e & 511;
        int y = rem >> 3;
        int s = rem & 7;
        int X = (x + dx + 62) & 63;
        size_t px = ((size_t)(bid - x + X)) * 64 + y;   // (n*64+X)*64 + y
        uint4v v = *((const uint4v*)(featT + px * 64) + s);
        *(uint4v*)(fl + dx * 8192 + y * 128 + ((s ^ (y & 7)) << 4)) = v;
    }
    if (tid < 192) {
        s_lds[tid] = 0.4886025119029199f * spin[(size_t)bid * 192 + tid];
    }
    __syncthreads();

    int lane = tid & 63;
    int wv4 = tid >> 6;            // 0..3
    int pair = wv4 >> 1;           // pixel half: 0 -> y 0-31, 1 -> y 32-63
    int role = wv4 & 1;            // 0: S000,S011,V; 1: T,U
    int col = lane & 31;           // N-col (w) and A-row (pixel within tile)
    int khalf = lane >> 5;         // K-half select
    int yb = pair << 5;

    f32x16 zz;
    #pragma unroll
    for (int i = 0; i < 16; ++i) zz[i] = 0.f;
    f32x16 aS000 = zz, aS011 = zz;
    f32x16 aV0 = zz, aV1 = zz, aV2 = zz;
    f32x16 aT0 = zz, aT1 = zz, aT2 = zz;
    f32x16 aU0 = zz, aU1 = zz, aU2 = zz;

    const unsigned char* bbase = bt + col * 32 + khalf * 16;

    if (role == 0) {
        short8 B0[3], B1[3];
        auto loadB = [&](int a, short8* B) {
            const unsigned char* p = bbase + a * 5120;
            B[0] = *(const short8*)(p);            // W000
            B[1] = *(const short8*)(p + 1024);     // W011
            B[2] = *(const short8*)(p + 2048);     // W110
        };
        auto body = [&](int a, short8* Bc, short8* Bn) {
            if (a + 1 < 25) loadB(a + 1, Bn);
            int ix = a / 5;
            int iy = a - ix * 5;
            int yn = (yb + col + iy + 62) & 63;
            const unsigned char* ab = fl + ix * 8192 + yn * 128;
            int xr = (yn & 7) << 4;
            short8 ax0 = *(const short8*)(ab + ((khalf << 4) ^ xr));
            short8 ac0 = *(const short8*)(ab + (((2 + khalf) << 4) ^ xr));
            short8 ac1 = *(const short8*)(ab + (((4 + khalf) << 4) ^ xr));
            short8 ac2 = *(const short8*)(ab + (((6 + khalf) << 4) ^ xr));
            aS000 = MFMA32(ax0, Bc[0], aS000);
            aS011 = MFMA32(ax0, Bc[1], aS011);
            aV0   = MFMA32(ac0, Bc[2], aV0);
            aV1   = MFMA32(ac1, Bc[2], aV1);
            aV2   = MFMA32(ac2, Bc[2], aV2);
        };
        loadB(0, B0);
        for (int ap = 0; ap < 25; ap += 2) {
            body(ap, B0, B1);
            if (ap + 1 < 25) body(ap + 1, B1, B0);
        }
        // hand S011 to role B
        #pragma unroll
        for (int r = 0; r < 16; ++r) sbuf[pair][r][lane] = aS011[r];
    } else {
        short8 B0[2], B1[2];
        auto loadB = [&](int a, short8* B) {
            const unsigned char* p = bbase + a * 5120;
            B[0] = *(const short8*)(p + 3072);     // W101
            B[1] = *(const short8*)(p + 4096);     // W111
        };
        auto body = [&](int a, short8* Bc, short8* Bn) {
            if (a + 1 < 25) loadB(a + 1, Bn);
            int ix = a / 5;
            int iy = a - ix * 5;
            int yn = (yb + col + iy + 62) & 63;
            const unsigned char* ab = fl + ix * 8192 + yn * 128;
            int xr = (yn & 7) << 4;
            short8 ac0 = *(const short8*)(ab + (((2 + khalf) << 4) ^ xr));
            short8 ac1 = *(const short8*)(ab + (((4 + khalf) << 4) ^ xr));
            short8 ac2 = *(const short8*)(ab + (((6 + khalf) << 4) ^ xr));
            aT0 = MFMA32(ac0, Bc[0], aT0);
            aU0 = MFMA32(ac0, Bc[1], aU0);
            aT1 = MFMA32(ac1, Bc[0], aT1);
            aU1 = MFMA32(ac1, Bc[1], aU1);
            aT2 = MFMA32(ac2, Bc[0], aT2);
            aU2 = MFMA32(ac2, Bc[1], aU2);
        };
        loadB(0, B0);
        for (int ap = 0; ap < 25; ap += 2) {
            body(ap, B0, B1);
            if (ap + 1 < 25) body(ap + 1, B1, B0);
        }
    }
    __syncthreads();

    // ---- epilogue: C/D row = (r&3) + 8*(r>>2) + 4*khalf, col = lane&31 ----
    int p0 = bid << 6;
    if (role == 0) {
        #pragma unroll
        for (int r = 0; r < 16; ++r) {
            int row = (r & 3) + ((r >> 2) << 3) + (khalf << 2);
            int y = yb + row;
            float s0 = s_lds[y * 3 + 0];
            float s1 = s_lds[y * 3 + 1];
            float s2 = s_lds[y * 3 + 2];
            float o0 = A0f * (SH0f * aS000[r]
                     + CG110f * (s0 * aV0[r] + s1 * aV1[r] + s2 * aV2[r]));
            out[(size_t)(p0 + y) * 128 + col] = o0;
        }
    } else {
        #pragma unroll
        for (int r = 0; r < 16; ++r) {
            int row = (r & 3) + ((r >> 2) << 3) + (khalf << 2);
            int y = yb + row;
            float s0 = s_lds[y * 3 + 0];
            float s1 = s_lds[y * 3 + 1];
            float s2 = s_lds[y * 3 + 2];
            float S011 = sbuf[pair][r][lane];
            float T0 = aT0[r], T1 = aT1[r], T2 = aT2[r];
            float U0 = aU0[r], U1 = aU1[r], U2 = aU2[r];
            float c0 = U1 * s2 - U2 * s1;
            float c1 = U2 * s0 - U0 * s2;
            float c2 = U0 * s1 - U1 * s0;
            float* op = out + (size_t)(p0 + y) * 128;
            op[32 + 3 * col + 0] = A1f * (s0 * S011 + SH0f * T0 + CG111f * c0);
            op[32 + 3 * col + 1] = A1f * (s1 * S011 + SH0f * T1 + CG111f * c1);
            op[32 + 3 * col + 2] = A1f * (s2 * S011 + SH0f * T2 + CG111f * c2);
        }
    }
}

extern "C" void kernel_launch(void* const* d_in, const int* in_sizes, int n_in,
                              void* d_out, int out_size, void* d_ws, size_t ws_size,
                              hipStream_t stream) {
    const float* feat = (const float*)d_in[0];
    const float* spin = (const float*)d_in[1];
    const float* W000 = (const float*)d_in[2];
    const float* W110 = (const float*)d_in[3];
    const float* W011 = (const float*)d_in[4];
    const float* W101 = (const float*)d_in[5];
    const float* W111 = (const float*)d_in[6];
    float* out = (float*)d_out;
    unsigned char* ws = (unsigned char*)d_ws;

    hipLaunchKernelGGL(prep_kernel, dim3(378), dim3(256), 0, stream,
                       feat, W000, W110, W011, W101, W111, ws);
    hipLaunchKernelGGL(spinconv_mfma_kernel, dim3(512), dim3(256), 0, stream,
                       ws, spin, out);
}